// Round 6
// baseline (408.913 us; speedup 1.0000x reference)
//
#include <hip/hip_runtime.h>
#include <math.h>

#define CCH 64
#define NLIST 64           // row-range partitions; list l runs on XCD l%8
#define BIN_CHUNK 4096     // edges per bin chunk (256 thr * 16)
#define BIN_EPT 16
#define SPILL_CAP_MAX 262144
#define MIN_LIST_CAP 49152

typedef float f4v __attribute__((ext_vector_type(4)));

__device__ __forceinline__ void nt_store_f4(float4 v, float4* p) {
    f4v x; x.x = v.x; x.y = v.y; x.z = v.z; x.w = v.w;
    __builtin_nontemporal_store(x, (f4v*)p);
}

__device__ __forceinline__ float4 max4f(float4 a, float4 b) {
    return make_float4(fmaxf(a.x, b.x), fmaxf(a.y, b.y),
                       fmaxf(a.z, b.z), fmaxf(a.w, b.w));
}

__device__ __forceinline__ void atomicMaxF(float* addr, float v) {
    if (v >= 0.0f) atomicMax((int*)addr, __float_as_int(v));
    else           atomicMin((unsigned int*)addr, __float_as_uint(v));
}

// ---------------- last-resort fallback (round-1 atomic path) ----------------

__global__ __launch_bounds__(256) void fill_neginf_kernel(float4* out, int n4) {
    int i = blockIdx.x * blockDim.x + threadIdx.x;
    int stride = gridDim.x * blockDim.x;
    const float4 v = make_float4(-INFINITY, -INFINITY, -INFINITY, -INFINITY);
    for (; i < n4; i += stride) out[i] = v;
}

__global__ __launch_bounds__(256) void scatter_max_kernel(
        const float4* __restrict__ feat4, const int* __restrict__ src,
        const int* __restrict__ tgt, const int* __restrict__ ntypes,
        float* __restrict__ out, int E) {
    int gid = blockIdx.x * blockDim.x + threadIdx.x;
    int e = gid >> 4, q = gid & 15;
    if (e >= E) return;
    int n0 = ntypes[e*3+0], n1 = ntypes[e*3+1], n2 = ntypes[e*3+2];
    if ((n0 | n1 | n2) < 0) return;
    float4 f = feat4[(size_t)tgt[e] * 16 + q];
    float* o = out + (size_t)src[e] * CCH + q * 4;
    atomicMaxF(o+0, f.x); atomicMaxF(o+1, f.y);
    atomicMaxF(o+2, f.z); atomicMaxF(o+3, f.w);
}

__global__ __launch_bounds__(256) void finalize_kernel(
        float4* out, int n4, const int* feat_depth, float* scalar_slot) {
    int i = blockIdx.x * blockDim.x + threadIdx.x;
    int stride = gridDim.x * blockDim.x;
    for (; i < n4; i += stride) {
        float4 v = out[i];
        v.x = (v.x == -INFINITY) ? 0.0f : v.x;
        v.y = (v.y == -INFINITY) ? 0.0f : v.y;
        v.z = (v.z == -INFINITY) ? 0.0f : v.z;
        v.w = (v.w == -INFINITY) ? 0.0f : v.w;
        out[i] = v;
    }
    if (blockIdx.x == 0 && threadIdx.x == 0)
        scalar_slot[0] = (float)(feat_depth[0] + 1);
}

// ---------------- binned bucket path ----------------

__global__ __launch_bounds__(256) void zero4_kernel(int4* p, long long n4) {
    long long i = blockIdx.x * (long long)blockDim.x + threadIdx.x;
    long long stride = gridDim.x * (long long)blockDim.x;
    const int4 z = make_int4(0, 0, 0, 0);
    for (; i < n4; i += stride) p[i] = z;
}

// Phase 1: partition passing edges into NLIST row-range lists.
// Per 4096-edge chunk: LDS counting sort by list id, then coalesced flush
// (one global atomicAdd per (chunk,list), ~512B contiguous runs).
__global__ __launch_bounds__(256) void bin_kernel(
        const int* __restrict__ src, const int* __restrict__ tgt,
        const int* __restrict__ ntypes,
        unsigned long long* __restrict__ lists, int listCap,
        int* __restrict__ gcur,
        unsigned long long* __restrict__ spill, int spillCap,
        int* __restrict__ spillCur,
        int shift, int E, int numChunks) {
    __shared__ unsigned long long pairs[BIN_CHUNK];
    __shared__ int hist[NLIST];
    __shared__ int lstart[NLIST];
    __shared__ int offs[NLIST];
    __shared__ int gbase[NLIST];
    __shared__ int sh_tot;

    for (int chunk = blockIdx.x; chunk < numChunks; chunk += gridDim.x) {
        long long e0 = (long long)chunk * BIN_CHUNK + (long long)threadIdx.x * BIN_EPT;

        if (threadIdx.x < NLIST) hist[threadIdx.x] = 0;
        __syncthreads();

        unsigned long long myPack[BIN_EPT];
        int myP[BIN_EPT];

        #pragma unroll
        for (int g = 0; g < BIN_EPT / 4; ++g) {
            long long eg = e0 + g * 4;
            int4 s4, t4, n0, n1, n2;
            if (eg + 4 <= E) {
                s4 = *(const int4*)(src + eg);
                t4 = *(const int4*)(tgt + eg);
                const int4* np = (const int4*)(ntypes + eg * 3);
                n0 = np[0]; n1 = np[1]; n2 = np[2];
            } else {
                s4 = make_int4(0,0,0,0); t4 = s4;
                n0 = make_int4(-1,-1,-1,-1); n1 = n0; n2 = n0;
                for (int k = 0; k < 4; ++k) {
                    long long e = eg + k;
                    if (e < E) {
                        (&s4.x)[k] = src[e]; (&t4.x)[k] = tgt[e];
                        int a = ntypes[e*3], b = ntypes[e*3+1], c = ntypes[e*3+2];
                        // pack mask into n0 slot
                        (&n0.x)[k] = a | b | c;
                        (&n1.x)[k] = 0; (&n2.x)[k] = 0;
                        continue;
                    }
                }
                // for tail path n0 already holds OR'd mask, n1/n2 zeroed
                int ntm[4] = {n0.x, n0.y, n0.z, n0.w};
                for (int k = 0; k < 4; ++k) {
                    int i = g*4 + k;
                    bool ok = (eg + k < E) && (ntm[k] >= 0);
                    int r = (&s4.x)[k];
                    myP[i] = ok ? (r >> shift) : -1;
                    myPack[i] = ((unsigned long long)(unsigned)r << 32) |
                                (unsigned)(&t4.x)[k];
                    if (ok) atomicAdd(&hist[myP[i]], 1);
                }
                continue;
            }
            int m0 = n0.x | n0.y | n0.z;            // edge eg+0
            int m1 = n0.w | n1.x | n1.y;            // edge eg+1
            int m2 = n1.z | n1.w | n2.x;            // edge eg+2
            int m3 = n2.y | n2.z | n2.w;            // edge eg+3
            int mm[4] = {m0, m1, m2, m3};
            int rr[4] = {s4.x, s4.y, s4.z, s4.w};
            int tt[4] = {t4.x, t4.y, t4.z, t4.w};
            #pragma unroll
            for (int k = 0; k < 4; ++k) {
                int i = g*4 + k;
                bool ok = mm[k] >= 0;
                myP[i] = ok ? (rr[k] >> shift) : -1;
                myPack[i] = ((unsigned long long)(unsigned)rr[k] << 32) |
                            (unsigned)tt[k];
                if (ok) atomicAdd(&hist[myP[i]], 1);
            }
        }
        __syncthreads();

        // exclusive scan of hist (one wave, 64 lanes)
        if (threadIdx.x < NLIST) {
            int h = hist[threadIdx.x];
            int incl = h;
            for (int o = 1; o < NLIST; o <<= 1) {
                int x = __shfl_up(incl, o, NLIST);
                if ((int)threadIdx.x >= o) incl += x;
            }
            lstart[threadIdx.x] = incl - h;
            offs[threadIdx.x]   = incl - h;
            if (threadIdx.x == NLIST - 1) sh_tot = incl;
            gbase[threadIdx.x] = atomicAdd(&gcur[threadIdx.x], h);
        }
        __syncthreads();

        // deposit into LDS-sorted order
        #pragma unroll
        for (int i = 0; i < BIN_EPT; ++i) {
            int p = myP[i];
            if (p >= 0) {
                int pos = atomicAdd(&offs[p], 1);
                pairs[pos] = myPack[i];
            }
        }
        __syncthreads();

        // coalesced flush
        int tot = sh_tot;
        for (int i = threadIdx.x; i < tot; i += 256) {
            unsigned long long pk = pairs[i];
            int p = (int)(pk >> 32) >> shift;
            int gpos = gbase[p] + (i - lstart[p]);
            if (gpos < listCap) {
                lists[(size_t)p * listCap + gpos] = pk;
            } else {
                int sp = atomicAdd(spillCur, 1);
                if (sp < spillCap) spill[sp] = pk;
            }
        }
        __syncthreads();
    }
}

// Phase 2: block b serves list b&63 -> runs on XCD (b&63)%8; its 512KB
// bucket slab stays in that XCD's L2, written back once. Counters live in
// a separate cnts[] array so atomics never touch the data lines.
template <int K>
__global__ __launch_bounds__(256) void deposit_kernel(
        const unsigned long long* __restrict__ lists, int listCap,
        const int* __restrict__ gcur, int* __restrict__ cnts,
        int* __restrict__ buckets,
        unsigned long long* __restrict__ spill, int spillCap,
        int* __restrict__ spillCur) {
    int l = blockIdx.x & (NLIST - 1);
    int sub = blockIdx.x / NLIST;
    int bpl = gridDim.x / NLIST;
    int cnt = gcur[l]; if (cnt > listCap) cnt = listCap;
    const unsigned long long* lst = lists + (size_t)l * listCap;
    const int CHNK = 256 * 4;
    for (int start = sub * CHNK; start < cnt; start += bpl * CHNK) {
        int i0 = start + (int)threadIdx.x * 4;
        if (i0 + 4 <= cnt) {
            ulonglong2 a = ((const ulonglong2*)(lst + i0))[0];
            ulonglong2 b = ((const ulonglong2*)(lst + i0))[1];
            unsigned long long pk[4] = {a.x, a.y, b.x, b.y};
            int r[4], t[4], c[4];
            #pragma unroll
            for (int k = 0; k < 4; ++k) {
                r[k] = (int)(pk[k] >> 32);
                t[k] = (int)(pk[k] & 0xffffffffu);
            }
            #pragma unroll
            for (int k = 0; k < 4; ++k) c[k] = atomicAdd(&cnts[r[k]], 1);
            #pragma unroll
            for (int k = 0; k < 4; ++k) {
                if (c[k] < K) {
                    buckets[(size_t)r[k] * K + c[k]] = t[k];
                } else {
                    int sp = atomicAdd(spillCur, 1);
                    if (sp < spillCap) spill[sp] = pk[k];
                }
            }
        } else {
            for (int i = i0; i < cnt && i < i0 + 4; ++i) {
                unsigned long long pk = lst[i];
                int r = (int)(pk >> 32), t = (int)(pk & 0xffffffffu);
                int c = atomicAdd(&cnts[r], 1);
                if (c < K) buckets[(size_t)r * K + c] = t;
                else {
                    int sp = atomicAdd(spillCur, 1);
                    if (sp < spillCap) spill[sp] = pk;
                }
            }
        }
    }
}

// One 16-lane group per row: count + 64B bucket line -> clamped unrolled gathers.
template <int K>
__global__ __launch_bounds__(256) void gather_bucket_kernel(
        const float4* __restrict__ feat4, const int* __restrict__ cnts,
        const int* __restrict__ buckets, float4* __restrict__ out4, int N,
        const int* __restrict__ feat_depth, float* __restrict__ scalar_slot) {
    int gid = blockIdx.x * blockDim.x + threadIdx.x;
    if (gid == 0) scalar_slot[0] = (float)(feat_depth[0] + 1);
    int r = gid >> 4, q = gid & 15;
    if (r >= N) return;
    const int* b = buckets + (size_t)r * K;
    int va[K];
    #pragma unroll
    for (int w = 0; w < K / 4; ++w) {
        int4 x = ((const int4*)b)[w];
        va[4*w+0] = x.x; va[4*w+1] = x.y; va[4*w+2] = x.z; va[4*w+3] = x.w;
    }
    int cnt = cnts[r];
    int m = cnt < K ? cnt : K;            // valid slots 0..m-1
    float4 acc;
    if (m <= 0) {
        acc = make_float4(0.0f, 0.0f, 0.0f, 0.0f);
    } else {
        int t0 = va[0];
        acc = feat4[(size_t)t0 * 16 + q];
        #pragma unroll
        for (int base = 1; base < K; base += 4) {
            if (base < m) {
                #pragma unroll
                for (int s = base; s < base + 4; ++s) {
                    if (s < K) {
                        int t = (s < m) ? va[s] : t0;   // clamped dup -> L1 hit
                        acc = max4f(acc, feat4[(size_t)t * 16 + q]);
                    }
                }
            }
        }
    }
    nt_store_f4(acc, out4 + (size_t)r * 16 + q);
}

// Resolve spilled edges (rare): atomic max on top of gather output (only raises).
__global__ __launch_bounds__(256) void spill_kernel(
        const float4* __restrict__ feat4,
        const unsigned long long* __restrict__ spill,
        const int* __restrict__ spillCur, int spillCap,
        float* __restrict__ out) {
    int n = *spillCur; if (n > spillCap) n = spillCap;
    long long total = (long long)n * 16;
    long long stride = (long long)gridDim.x * blockDim.x;
    for (long long i = blockIdx.x * (long long)blockDim.x + threadIdx.x;
         i < total; i += stride) {
        int e = (int)(i >> 4), q = (int)(i & 15);
        unsigned long long pk = spill[e];
        int r = (int)(pk >> 32);
        int t = (int)(pk & 0xffffffffu);
        float4 f = feat4[(size_t)t * 16 + q];
        float* o = out + (size_t)r * CCH + q * 4;
        atomicMaxF(o+0, f.x); atomicMaxF(o+1, f.y);
        atomicMaxF(o+2, f.z); atomicMaxF(o+3, f.w);
    }
}

// If the spill list overflowed, rescan ALL edges with atomic max — idempotent.
__global__ __launch_bounds__(256) void repair_kernel(
        const float4* __restrict__ feat4, const int* __restrict__ src,
        const int* __restrict__ tgt, const int* __restrict__ ntypes,
        const int* __restrict__ spillCur, int spillCap,
        float* __restrict__ out, int E) {
    if (*spillCur <= spillCap) return;
    long long total = (long long)E * 16;
    long long stride = (long long)gridDim.x * blockDim.x;
    for (long long i = blockIdx.x * (long long)blockDim.x + threadIdx.x;
         i < total; i += stride) {
        int e = (int)(i >> 4), q = (int)(i & 15);
        if ((ntypes[e*3] | ntypes[e*3+1] | ntypes[e*3+2]) < 0) continue;
        float4 f = feat4[(size_t)tgt[e] * 16 + q];
        float* o = out + (size_t)src[e] * CCH + q * 4;
        atomicMaxF(o+0, f.x); atomicMaxF(o+1, f.y);
        atomicMaxF(o+2, f.z); atomicMaxF(o+3, f.w);
    }
}

extern "C" void kernel_launch(void* const* d_in, const int* in_sizes, int n_in,
                              void* d_out, int out_size, void* d_ws, size_t ws_size,
                              hipStream_t stream) {
    const float* feat       = (const float*)d_in[0];
    const int*   src_ids    = (const int*)d_in[1];
    const int*   tgt_ids    = (const int*)d_in[2];
    const int*   ntypes     = (const int*)d_in[3];
    const int*   feat_depth = (const int*)d_in[5];
    float* out = (float*)d_out;

    const int E = in_sizes[1];
    const int nout_elems = out_size - 1;
    const int N = nout_elems / CCH;      // output rows
    const int n4 = nout_elems / 4;

    // list shift: rows-per-list = 2^shift, covering N with <= 64 lists
    int shift = 0;
    while (((long long)(N - 1) >> shift) > (NLIST - 1)) ++shift;

    // ws layout (ints): cnts[N] | gcur[64] | spillCurBlk[16] |
    //                   spill[2*spillCap] | buckets[N*K] | lists[2*64*listCap]
    size_t wsInts = ws_size / sizeof(int);
    size_t baseInts = (size_t)N + NLIST + 16;

    int K = 0, listCap = 0, spillCap = 0;
    for (int k = 16; k >= 8 && K == 0; k -= 8) {
        long long bucketInts = (long long)N * k;
        for (int sc = SPILL_CAP_MAX; sc >= 65536; sc >>= 1) {
            long long rem = (long long)wsInts - (long long)baseInts -
                            bucketInts - 2ll * sc;
            if (rem <= 0) continue;
            long long lc = (rem / (2ll * NLIST)) & ~1ll;
            if (lc > 69632) lc = 69632;
            if (lc >= MIN_LIST_CAP) { K = k; listCap = (int)lc; spillCap = sc; break; }
        }
    }

    if (K == 0 || (N & 3) != 0) {
        // last-resort: atomic scatter-max
        fill_neginf_kernel<<<2048, 256, 0, stream>>>((float4*)out, n4);
        long long total = (long long)E * 16;
        int blocks = (int)((total + 255) / 256);
        scatter_max_kernel<<<blocks, 256, 0, stream>>>(
            (const float4*)feat, src_ids, tgt_ids, ntypes, out, E);
        finalize_kernel<<<2048, 256, 0, stream>>>(
            (float4*)out, n4, feat_depth, out + nout_elems);
        return;
    }

    int* cnts     = (int*)d_ws;
    int* gcur     = cnts + N;
    int* spillCur = gcur + NLIST;
    unsigned long long* spill = (unsigned long long*)(spillCur + 16);
    int* buckets  = (int*)(spill + spillCap);
    unsigned long long* lists = (unsigned long long*)(buckets + (size_t)N * K);

    // zero cnts + gcur + spillCur (buckets/lists need no init)
    zero4_kernel<<<512, 256, 0, stream>>>((int4*)d_ws, (long long)(N + NLIST + 16) / 4);

    int numChunks = (E + BIN_CHUNK - 1) / BIN_CHUNK;
    int binGrid = numChunks < 4096 ? numChunks : 4096;
    bin_kernel<<<binGrid, 256, 0, stream>>>(
        src_ids, tgt_ids, ntypes, lists, listCap, gcur,
        spill, spillCap, spillCur, shift, E, numChunks);

    long long gthreads = (long long)N * 16;
    int gBlocks = (int)((gthreads + 255) / 256);

    if (K == 16) {
        deposit_kernel<16><<<2048, 256, 0, stream>>>(
            lists, listCap, gcur, cnts, buckets, spill, spillCap, spillCur);
        gather_bucket_kernel<16><<<gBlocks, 256, 0, stream>>>(
            (const float4*)feat, cnts, buckets, (float4*)out, N,
            feat_depth, out + nout_elems);
    } else {
        deposit_kernel<8><<<2048, 256, 0, stream>>>(
            lists, listCap, gcur, cnts, buckets, spill, spillCap, spillCur);
        gather_bucket_kernel<8><<<gBlocks, 256, 0, stream>>>(
            (const float4*)feat, cnts, buckets, (float4*)out, N,
            feat_depth, out + nout_elems);
    }

    spill_kernel<<<2048, 256, 0, stream>>>(
        (const float4*)feat, spill, spillCur, spillCap, out);
    repair_kernel<<<4096, 256, 0, stream>>>(
        (const float4*)feat, src_ids, tgt_ids, ntypes,
        spillCur, spillCap, out, E);
}

// Round 8
// 214.635 us; speedup vs baseline: 1.9052x; 1.9052x over previous
//
#include <hip/hip_runtime.h>
#include <math.h>

#define CCH 64
#define NLIST 64           // bin1 partitions
#define BIN_CHUNK 4096     // edges per bin chunk (256 thr * 16)
#define BIN_EPT 16
#define WROWS 256          // rows per window (fused LDS tile)
#define WSHIFT 8           // log2(WROWS)
#define CAP2 2048          // pairs per window sublist (mean ~1435, +16 sigma)
#define SPILL_CAP 131072

typedef float f4v __attribute__((ext_vector_type(4)));

__device__ __forceinline__ void nt_store_f4(float4 v, float4* p) {
    f4v x; x.x = v.x; x.y = v.y; x.z = v.z; x.w = v.w;
    __builtin_nontemporal_store(x, (f4v*)p);
}

__device__ __forceinline__ void atomicMaxF(float* addr, float v) {
    if (v >= 0.0f) atomicMax((int*)addr, __float_as_int(v));
    else           atomicMin((unsigned int*)addr, __float_as_uint(v));
}

// ---------------- last-resort fallback (round-1 atomic path) ----------------

__global__ __launch_bounds__(256) void fill_neginf_kernel(float4* out, int n4) {
    int i = blockIdx.x * blockDim.x + threadIdx.x;
    int stride = gridDim.x * blockDim.x;
    const float4 v = make_float4(-INFINITY, -INFINITY, -INFINITY, -INFINITY);
    for (; i < n4; i += stride) out[i] = v;
}

__global__ __launch_bounds__(256) void scatter_max_kernel(
        const float4* __restrict__ feat4, const int* __restrict__ src,
        const int* __restrict__ tgt, const int* __restrict__ ntypes,
        float* __restrict__ out, int E) {
    int gid = blockIdx.x * blockDim.x + threadIdx.x;
    int e = gid >> 4, q = gid & 15;
    if (e >= E) return;
    int n0 = ntypes[e*3+0], n1 = ntypes[e*3+1], n2 = ntypes[e*3+2];
    if ((n0 | n1 | n2) < 0) return;
    float4 f = feat4[(size_t)tgt[e] * 16 + q];
    float* o = out + (size_t)src[e] * CCH + q * 4;
    atomicMaxF(o+0, f.x); atomicMaxF(o+1, f.y);
    atomicMaxF(o+2, f.z); atomicMaxF(o+3, f.w);
}

__global__ __launch_bounds__(256) void finalize_kernel(
        float4* out, int n4, const int* feat_depth, float* scalar_slot) {
    int i = blockIdx.x * blockDim.x + threadIdx.x;
    int stride = gridDim.x * blockDim.x;
    for (; i < n4; i += stride) {
        float4 v = out[i];
        v.x = (v.x == -INFINITY) ? 0.0f : v.x;
        v.y = (v.y == -INFINITY) ? 0.0f : v.y;
        v.z = (v.z == -INFINITY) ? 0.0f : v.z;
        v.w = (v.w == -INFINITY) ? 0.0f : v.w;
        out[i] = v;
    }
    if (blockIdx.x == 0 && threadIdx.x == 0)
        scalar_slot[0] = (float)(feat_depth[0] + 1);
}

// ---------------- binned LDS-reduce path ----------------

__global__ __launch_bounds__(256) void zero4_kernel(int4* p, long long n4) {
    long long i = blockIdx.x * (long long)blockDim.x + threadIdx.x;
    long long stride = gridDim.x * (long long)blockDim.x;
    const int4 z = make_int4(0, 0, 0, 0);
    for (; i < n4; i += stride) p[i] = z;
}

// Phase 1: partition passing edges into NLIST row-range lists (coalesced runs).
__global__ __launch_bounds__(256) void bin_kernel(
        const int* __restrict__ src, const int* __restrict__ tgt,
        const int* __restrict__ ntypes,
        unsigned long long* __restrict__ lists, int listCap,
        int* __restrict__ gcur,
        unsigned long long* __restrict__ spill, int spillCap,
        int* __restrict__ spillCur,
        int shift, int E, int numChunks) {
    __shared__ unsigned long long pairs[BIN_CHUNK];
    __shared__ int hist[NLIST];
    __shared__ int lstart[NLIST];
    __shared__ int offs[NLIST];
    __shared__ int gbase[NLIST];
    __shared__ int sh_tot;

    for (int chunk = blockIdx.x; chunk < numChunks; chunk += gridDim.x) {
        long long e0 = (long long)chunk * BIN_CHUNK + (long long)threadIdx.x * BIN_EPT;

        if (threadIdx.x < NLIST) hist[threadIdx.x] = 0;
        __syncthreads();

        unsigned long long myPack[BIN_EPT];
        int myP[BIN_EPT];

        #pragma unroll
        for (int g = 0; g < BIN_EPT / 4; ++g) {
            long long eg = e0 + g * 4;
            int4 s4, t4, n0, n1, n2;
            if (eg + 4 <= E) {
                s4 = *(const int4*)(src + eg);
                t4 = *(const int4*)(tgt + eg);
                const int4* np = (const int4*)(ntypes + eg * 3);
                n0 = np[0]; n1 = np[1]; n2 = np[2];
            } else {
                s4 = make_int4(0,0,0,0); t4 = s4;
                n0 = make_int4(-1,-1,-1,-1); n1 = n0; n2 = n0;
                for (int k = 0; k < 4; ++k) {
                    long long e = eg + k;
                    if (e < E) {
                        (&s4.x)[k] = src[e]; (&t4.x)[k] = tgt[e];
                        int a = ntypes[e*3], b = ntypes[e*3+1], c = ntypes[e*3+2];
                        (&n0.x)[k] = a | b | c;
                        (&n1.x)[k] = 0; (&n2.x)[k] = 0;
                        continue;
                    }
                }
                int ntm[4] = {n0.x, n0.y, n0.z, n0.w};
                for (int k = 0; k < 4; ++k) {
                    int i = g*4 + k;
                    bool ok = (eg + k < E) && (ntm[k] >= 0);
                    int r = (&s4.x)[k];
                    myP[i] = ok ? (r >> shift) : -1;
                    myPack[i] = ((unsigned long long)(unsigned)r << 32) |
                                (unsigned)(&t4.x)[k];
                    if (ok) atomicAdd(&hist[myP[i]], 1);
                }
                continue;
            }
            int m0 = n0.x | n0.y | n0.z;
            int m1 = n0.w | n1.x | n1.y;
            int m2 = n1.z | n1.w | n2.x;
            int m3 = n2.y | n2.z | n2.w;
            int mm[4] = {m0, m1, m2, m3};
            int rr[4] = {s4.x, s4.y, s4.z, s4.w};
            int tt[4] = {t4.x, t4.y, t4.z, t4.w};
            #pragma unroll
            for (int k = 0; k < 4; ++k) {
                int i = g*4 + k;
                bool ok = mm[k] >= 0;
                myP[i] = ok ? (rr[k] >> shift) : -1;
                myPack[i] = ((unsigned long long)(unsigned)rr[k] << 32) |
                            (unsigned)tt[k];
                if (ok) atomicAdd(&hist[myP[i]], 1);
            }
        }
        __syncthreads();

        if (threadIdx.x < NLIST) {
            int h = hist[threadIdx.x];
            int incl = h;
            for (int o = 1; o < NLIST; o <<= 1) {
                int x = __shfl_up(incl, o, NLIST);
                if ((int)threadIdx.x >= o) incl += x;
            }
            lstart[threadIdx.x] = incl - h;
            offs[threadIdx.x]   = incl - h;
            if (threadIdx.x == NLIST - 1) sh_tot = incl;
            gbase[threadIdx.x] = atomicAdd(&gcur[threadIdx.x], h);
        }
        __syncthreads();

        #pragma unroll
        for (int i = 0; i < BIN_EPT; ++i) {
            int p = myP[i];
            if (p >= 0) {
                int pos = atomicAdd(&offs[p], 1);
                pairs[pos] = myPack[i];
            }
        }
        __syncthreads();

        int tot = sh_tot;
        for (int i = threadIdx.x; i < tot; i += 256) {
            unsigned long long pk = pairs[i];
            int p = (int)(pk >> 32) >> shift;
            int gpos = gbase[p] + (i - lstart[p]);
            if (gpos < listCap) {
                lists[(size_t)p * listCap + gpos] = pk;
            } else {
                int sp = atomicAdd(spillCur, 1);
                if (sp < spillCap) spill[sp] = pk;
            }
        }
        __syncthreads();
    }
}

// Phase 2: re-bin each list into per-window sublists (sequential read,
// LDS sort into <=32 bins, coalesced flush runs).
__global__ __launch_bounds__(256) void bin2_kernel(
        const unsigned long long* __restrict__ lists, int listCap,
        const int* __restrict__ gcur,
        unsigned long long* __restrict__ sub, int* __restrict__ cur2,
        unsigned long long* __restrict__ spill, int spillCap,
        int* __restrict__ spillCur, int wpl) {
    __shared__ unsigned long long pr[BIN_CHUNK];
    __shared__ int hist[32], lstart[32], offs[32], gbase[32];
    __shared__ int sh_tot;
    int l = blockIdx.x & (NLIST - 1);
    int s = blockIdx.x >> 6;                 // 16 chunk-parallel subs
    int cnt = gcur[l]; if (cnt > listCap) cnt = listCap;
    const unsigned long long* lst = lists + (size_t)l * listCap;
    int wmask = wpl - 1;

    for (int start = s * BIN_CHUNK; start < cnt; start += 16 * BIN_CHUNK) {
        int n = cnt - start; if (n > BIN_CHUNK) n = BIN_CHUNK;
        if (threadIdx.x < 32) hist[threadIdx.x] = 0;
        __syncthreads();

        unsigned long long my[BIN_EPT]; int myw[BIN_EPT];
        #pragma unroll
        for (int k = 0; k < BIN_EPT; ++k) {
            int i = k * 256 + threadIdx.x;
            if (i < n) {
                unsigned long long pk = lst[start + i];
                int w = ((int)(pk >> 32) >> WSHIFT) & wmask;
                my[k] = pk; myw[k] = w;
                atomicAdd(&hist[w], 1);
            } else myw[k] = -1;
        }
        __syncthreads();

        if (threadIdx.x == 0) {
            int run = 0;
            for (int w = 0; w < wpl; ++w) {
                lstart[w] = run; offs[w] = run; run += hist[w];
            }
            sh_tot = run;
        }
        __syncthreads();
        if ((int)threadIdx.x < wpl)
            gbase[threadIdx.x] =
                atomicAdd(&cur2[l * wpl + threadIdx.x], hist[threadIdx.x]);
        __syncthreads();

        #pragma unroll
        for (int k = 0; k < BIN_EPT; ++k) {
            if (myw[k] >= 0) {
                int pos = atomicAdd(&offs[myw[k]], 1);
                pr[pos] = my[k];
            }
        }
        __syncthreads();

        int tot = sh_tot;
        for (int i = threadIdx.x; i < tot; i += 256) {
            unsigned long long pk = pr[i];
            int w = ((int)(pk >> 32) >> WSHIFT) & wmask;
            int gpos = gbase[w] + (i - lstart[w]);
            if (gpos < CAP2) {
                sub[((size_t)(l * wpl + w)) * CAP2 + gpos] = pk;
            } else {
                int sp = atomicAdd(spillCur, 1);
                if (sp < spillCap) spill[sp] = pk;
            }
        }
        __syncthreads();
    }
}

// Fused gather + LDS max-reduce + single coalesced write-out.
// One block per 256-row window; 64 KB LDS tile of order-preserving uint keys.
// REPLAY-SAFETY: sub's content at a fixed address varies between calls
// (atomic placement order), so pairs are loaded PER-LANE (vector path,
// invalidated per dispatch) and broadcast via __shfl — never via a
// wave-uniform load that could compile to s_load through the scalar K$.
__global__ __launch_bounds__(512) void fused_kernel(
        const float* __restrict__ feat,
        const unsigned long long* __restrict__ sub,
        const int* __restrict__ cur2,
        float4* __restrict__ out4,
        const int* __restrict__ feat_depth, float* __restrict__ scalar_slot) {
    __shared__ unsigned int tile[WROWS * CCH];   // 64 KB
    int w = blockIdx.x;
    if (w == 0 && threadIdx.x == 0)
        scalar_slot[0] = (float)(feat_depth[0] + 1);

    for (int i = threadIdx.x; i < WROWS * CCH; i += 512) tile[i] = 0u;
    __syncthreads();

    int cnt = cur2[w]; if (cnt > CAP2) cnt = CAP2;
    const unsigned long long* sl = sub + (size_t)w * CAP2;
    int lane = threadIdx.x & 63;
    int wid = threadIdx.x >> 6;                  // 8 waves

    for (int i0 = wid * 64; i0 < cnt; i0 += 8 * 64) {
        int m = cnt - i0; if (m > 64) m = 64;
        // coalesced 512B per-lane pair load
        unsigned long long own = (lane < m) ? sl[i0 + lane] : 0ull;
        int j = 0;
        for (; j + 8 <= m; j += 8) {
            unsigned long long pk[8];
            #pragma unroll
            for (int u = 0; u < 8; ++u) pk[u] = __shfl(own, j + u);
            float f[8]; int rl[8];
            #pragma unroll
            for (int u = 0; u < 8; ++u) {
                int t = (int)(pk[u] & 0xffffffffu);
                rl[u] = ((int)(pk[u] >> 32)) & (WROWS - 1);
                f[u] = feat[(size_t)t * CCH + lane];      // 256B coalesced
            }
            #pragma unroll
            for (int u = 0; u < 8; ++u) {
                unsigned int b = __float_as_uint(f[u]);
                unsigned int key = b ^ ((unsigned int)((int)b >> 31) | 0x80000000u);
                atomicMax(&tile[rl[u] * CCH + lane], key); // ds_max, 2 ln/bank
            }
        }
        for (; j < m; ++j) {
            unsigned long long pk = __shfl(own, j);
            int t = (int)(pk & 0xffffffffu);
            int rl = ((int)(pk >> 32)) & (WROWS - 1);
            unsigned int b = __float_as_uint(feat[(size_t)t * CCH + lane]);
            unsigned int key = b ^ ((unsigned int)((int)b >> 31) | 0x80000000u);
            atomicMax(&tile[rl * CCH + lane], key);
        }
    }
    __syncthreads();

    const uint4* t4 = (const uint4*)tile;
    for (int i = threadIdx.x; i < WROWS * CCH / 4; i += 512) {
        uint4 k = t4[i];
        float4 v;
        v.x = (k.x == 0u) ? 0.0f
              : __uint_as_float((k.x & 0x80000000u) ? (k.x ^ 0x80000000u) : ~k.x);
        v.y = (k.y == 0u) ? 0.0f
              : __uint_as_float((k.y & 0x80000000u) ? (k.y ^ 0x80000000u) : ~k.y);
        v.z = (k.z == 0u) ? 0.0f
              : __uint_as_float((k.z & 0x80000000u) ? (k.z ^ 0x80000000u) : ~k.z);
        v.w = (k.w == 0u) ? 0.0f
              : __uint_as_float((k.w & 0x80000000u) ? (k.w ^ 0x80000000u) : ~k.w);
        nt_store_f4(v, out4 + (size_t)w * (WROWS * (CCH / 4)) + i);
    }
}

// Resolve spilled edges (rare): atomic max on top of fused output (only raises).
__global__ __launch_bounds__(256) void spill_kernel(
        const float4* __restrict__ feat4,
        const unsigned long long* __restrict__ spill,
        const int* __restrict__ spillCur, int spillCap,
        float* __restrict__ out) {
    int n = *spillCur; if (n > spillCap) n = spillCap;
    long long total = (long long)n * 16;
    long long stride = (long long)gridDim.x * blockDim.x;
    for (long long i = blockIdx.x * (long long)blockDim.x + threadIdx.x;
         i < total; i += stride) {
        int e = (int)(i >> 4), q = (int)(i & 15);
        unsigned long long pk = spill[e];
        int r = (int)(pk >> 32);
        int t = (int)(pk & 0xffffffffu);
        float4 f = feat4[(size_t)t * 16 + q];
        float* o = out + (size_t)r * CCH + q * 4;
        atomicMaxF(o+0, f.x); atomicMaxF(o+1, f.y);
        atomicMaxF(o+2, f.z); atomicMaxF(o+3, f.w);
    }
}

// If the spill list overflowed, rescan ALL edges with atomic max — idempotent.
__global__ __launch_bounds__(256) void repair_kernel(
        const float4* __restrict__ feat4, const int* __restrict__ src,
        const int* __restrict__ tgt, const int* __restrict__ ntypes,
        const int* __restrict__ spillCur, int spillCap,
        float* __restrict__ out, int E) {
    if (*spillCur <= spillCap) return;
    long long total = (long long)E * 16;
    long long stride = (long long)gridDim.x * blockDim.x;
    for (long long i = blockIdx.x * (long long)blockDim.x + threadIdx.x;
         i < total; i += stride) {
        int e = (int)(i >> 4), q = (int)(i & 15);
        if ((ntypes[e*3] | ntypes[e*3+1] | ntypes[e*3+2]) < 0) continue;
        float4 f = feat4[(size_t)tgt[e] * 16 + q];
        float* o = out + (size_t)src[e] * CCH + q * 4;
        atomicMaxF(o+0, f.x); atomicMaxF(o+1, f.y);
        atomicMaxF(o+2, f.z); atomicMaxF(o+3, f.w);
    }
}

extern "C" void kernel_launch(void* const* d_in, const int* in_sizes, int n_in,
                              void* d_out, int out_size, void* d_ws, size_t ws_size,
                              hipStream_t stream) {
    const float* feat       = (const float*)d_in[0];
    const int*   src_ids    = (const int*)d_in[1];
    const int*   tgt_ids    = (const int*)d_in[2];
    const int*   ntypes     = (const int*)d_in[3];
    const int*   feat_depth = (const int*)d_in[5];
    float* out = (float*)d_out;

    const int E = in_sizes[1];
    const int nout_elems = out_size - 1;
    const int N = nout_elems / CCH;      // output rows
    const int n4 = nout_elems / 4;

    // bin1 shift: rows-per-list = 2^shift1, <= 64 lists
    int shift1 = 0;
    while (((long long)(N - 1) >> shift1) > (NLIST - 1)) ++shift1;
    int wpl = (shift1 >= WSHIFT) ? (1 << (shift1 - WSHIFT)) : 0; // windows/list
    int windows = (wpl > 0) ? ((N + WROWS - 1) >> WSHIFT) : 0;

    // ws ints: gcur[64] | cur2[windows] | spillCur[16] | spill u64[SPILL_CAP]
    //          | lists1 u64[64*LC1] | sub u64[windows*CAP2]
    size_t wsInts = ws_size / sizeof(int);
    size_t zeroInts = (size_t)NLIST + windows + 16;
    int LC1 = 0;
    if (wpl >= 1 && wpl <= 32 && windows > 0 && (N % WROWS) == 0 &&
        (zeroInts % 4) == 0) {
        for (int lc = 69632; lc >= 49152; lc -= 20480) {
            size_t need = zeroInts + 2ull * SPILL_CAP +
                          2ull * NLIST * lc + 2ull * windows * CAP2;
            if (need <= wsInts) { LC1 = lc; break; }
        }
    }

    if (LC1 == 0) {
        // last-resort: atomic scatter-max
        fill_neginf_kernel<<<2048, 256, 0, stream>>>((float4*)out, n4);
        long long total = (long long)E * 16;
        int blocks = (int)((total + 255) / 256);
        scatter_max_kernel<<<blocks, 256, 0, stream>>>(
            (const float4*)feat, src_ids, tgt_ids, ntypes, out, E);
        finalize_kernel<<<2048, 256, 0, stream>>>(
            (float4*)out, n4, feat_depth, out + nout_elems);
        return;
    }

    int* gcur     = (int*)d_ws;
    int* cur2     = gcur + NLIST;
    int* spillCur = cur2 + windows;
    unsigned long long* spill  = (unsigned long long*)(spillCur + 16);
    unsigned long long* lists1 = spill + SPILL_CAP;
    unsigned long long* sub    = lists1 + (size_t)NLIST * LC1;

    zero4_kernel<<<16, 256, 0, stream>>>((int4*)d_ws, (long long)(zeroInts / 4));

    int numChunks = (E + BIN_CHUNK - 1) / BIN_CHUNK;
    int binGrid = numChunks < 4096 ? numChunks : 4096;
    bin_kernel<<<binGrid, 256, 0, stream>>>(
        src_ids, tgt_ids, ntypes, lists1, LC1, gcur,
        spill, SPILL_CAP, spillCur, shift1, E, numChunks);

    bin2_kernel<<<NLIST * 16, 256, 0, stream>>>(
        lists1, LC1, gcur, sub, cur2, spill, SPILL_CAP, spillCur, wpl);

    fused_kernel<<<windows, 512, 0, stream>>>(
        feat, sub, cur2, (float4*)out, feat_depth, out + nout_elems);

    spill_kernel<<<2048, 256, 0, stream>>>(
        (const float4*)feat, spill, spillCur, SPILL_CAP, out);
    repair_kernel<<<4096, 256, 0, stream>>>(
        (const float4*)feat, src_ids, tgt_ids, ntypes,
        spillCur, SPILL_CAP, out, E);
}

// Round 9
// 205.600 us; speedup vs baseline: 1.9889x; 1.0439x over previous
//
#include <hip/hip_runtime.h>
#include <math.h>

#define CCH 64
#define NLIST 64           // bin1 partitions
#define BIN_CHUNK 4096     // edges per bin chunk (256 thr * 16)
#define BIN_EPT 16
#define WROWS 128          // rows per window (fused LDS tile = 32 KB)
#define WSHIFT 7           // log2(WROWS)
#define NB2 64             // bin2 sublists per list (wpl <= NB2)
#define CAP2 1280          // pairs per window sublist (mean ~717, +20 sigma)
#define SPILL_CAP 131072

typedef float f4v __attribute__((ext_vector_type(4)));

__device__ __forceinline__ void nt_store_f4(float4 v, float4* p) {
    f4v x; x.x = v.x; x.y = v.y; x.z = v.z; x.w = v.w;
    __builtin_nontemporal_store(x, (f4v*)p);
}

__device__ __forceinline__ void atomicMaxF(float* addr, float v) {
    if (v >= 0.0f) atomicMax((int*)addr, __float_as_int(v));
    else           atomicMin((unsigned int*)addr, __float_as_uint(v));
}

// ---------------- last-resort fallback (round-1 atomic path) ----------------

__global__ __launch_bounds__(256) void fill_neginf_kernel(float4* out, int n4) {
    int i = blockIdx.x * blockDim.x + threadIdx.x;
    int stride = gridDim.x * blockDim.x;
    const float4 v = make_float4(-INFINITY, -INFINITY, -INFINITY, -INFINITY);
    for (; i < n4; i += stride) out[i] = v;
}

__global__ __launch_bounds__(256) void scatter_max_kernel(
        const float4* __restrict__ feat4, const int* __restrict__ src,
        const int* __restrict__ tgt, const int* __restrict__ ntypes,
        float* __restrict__ out, int E) {
    int gid = blockIdx.x * blockDim.x + threadIdx.x;
    int e = gid >> 4, q = gid & 15;
    if (e >= E) return;
    int n0 = ntypes[e*3+0], n1 = ntypes[e*3+1], n2 = ntypes[e*3+2];
    if ((n0 | n1 | n2) < 0) return;
    float4 f = feat4[(size_t)tgt[e] * 16 + q];
    float* o = out + (size_t)src[e] * CCH + q * 4;
    atomicMaxF(o+0, f.x); atomicMaxF(o+1, f.y);
    atomicMaxF(o+2, f.z); atomicMaxF(o+3, f.w);
}

__global__ __launch_bounds__(256) void finalize_kernel(
        float4* out, int n4, const int* feat_depth, float* scalar_slot) {
    int i = blockIdx.x * blockDim.x + threadIdx.x;
    int stride = gridDim.x * blockDim.x;
    for (; i < n4; i += stride) {
        float4 v = out[i];
        v.x = (v.x == -INFINITY) ? 0.0f : v.x;
        v.y = (v.y == -INFINITY) ? 0.0f : v.y;
        v.z = (v.z == -INFINITY) ? 0.0f : v.z;
        v.w = (v.w == -INFINITY) ? 0.0f : v.w;
        out[i] = v;
    }
    if (blockIdx.x == 0 && threadIdx.x == 0)
        scalar_slot[0] = (float)(feat_depth[0] + 1);
}

// ---------------- binned LDS-reduce path ----------------

__global__ __launch_bounds__(256) void zero4_kernel(int4* p, long long n4) {
    long long i = blockIdx.x * (long long)blockDim.x + threadIdx.x;
    long long stride = gridDim.x * (long long)blockDim.x;
    const int4 z = make_int4(0, 0, 0, 0);
    for (; i < n4; i += stride) p[i] = z;
}

// Phase 1: partition passing edges into NLIST row-range lists (coalesced runs).
__global__ __launch_bounds__(256) void bin_kernel(
        const int* __restrict__ src, const int* __restrict__ tgt,
        const int* __restrict__ ntypes,
        unsigned long long* __restrict__ lists, int listCap,
        int* __restrict__ gcur,
        unsigned long long* __restrict__ spill, int spillCap,
        int* __restrict__ spillCur,
        int shift, int E, int numChunks) {
    __shared__ unsigned long long pairs[BIN_CHUNK];
    __shared__ int hist[NLIST];
    __shared__ int lstart[NLIST];
    __shared__ int offs[NLIST];
    __shared__ int gbase[NLIST];
    __shared__ int sh_tot;

    for (int chunk = blockIdx.x; chunk < numChunks; chunk += gridDim.x) {
        long long e0 = (long long)chunk * BIN_CHUNK + (long long)threadIdx.x * BIN_EPT;

        if (threadIdx.x < NLIST) hist[threadIdx.x] = 0;
        __syncthreads();

        unsigned long long myPack[BIN_EPT];
        int myP[BIN_EPT];

        #pragma unroll
        for (int g = 0; g < BIN_EPT / 4; ++g) {
            long long eg = e0 + g * 4;
            int4 s4, t4, n0, n1, n2;
            if (eg + 4 <= E) {
                s4 = *(const int4*)(src + eg);
                t4 = *(const int4*)(tgt + eg);
                const int4* np = (const int4*)(ntypes + eg * 3);
                n0 = np[0]; n1 = np[1]; n2 = np[2];
            } else {
                s4 = make_int4(0,0,0,0); t4 = s4;
                n0 = make_int4(-1,-1,-1,-1); n1 = n0; n2 = n0;
                for (int k = 0; k < 4; ++k) {
                    long long e = eg + k;
                    if (e < E) {
                        (&s4.x)[k] = src[e]; (&t4.x)[k] = tgt[e];
                        int a = ntypes[e*3], b = ntypes[e*3+1], c = ntypes[e*3+2];
                        (&n0.x)[k] = a | b | c;
                        (&n1.x)[k] = 0; (&n2.x)[k] = 0;
                        continue;
                    }
                }
                int ntm[4] = {n0.x, n0.y, n0.z, n0.w};
                for (int k = 0; k < 4; ++k) {
                    int i = g*4 + k;
                    bool ok = (eg + k < E) && (ntm[k] >= 0);
                    int r = (&s4.x)[k];
                    myP[i] = ok ? (r >> shift) : -1;
                    myPack[i] = ((unsigned long long)(unsigned)r << 32) |
                                (unsigned)(&t4.x)[k];
                    if (ok) atomicAdd(&hist[myP[i]], 1);
                }
                continue;
            }
            int m0 = n0.x | n0.y | n0.z;
            int m1 = n0.w | n1.x | n1.y;
            int m2 = n1.z | n1.w | n2.x;
            int m3 = n2.y | n2.z | n2.w;
            int mm[4] = {m0, m1, m2, m3};
            int rr[4] = {s4.x, s4.y, s4.z, s4.w};
            int tt[4] = {t4.x, t4.y, t4.z, t4.w};
            #pragma unroll
            for (int k = 0; k < 4; ++k) {
                int i = g*4 + k;
                bool ok = mm[k] >= 0;
                myP[i] = ok ? (rr[k] >> shift) : -1;
                myPack[i] = ((unsigned long long)(unsigned)rr[k] << 32) |
                            (unsigned)tt[k];
                if (ok) atomicAdd(&hist[myP[i]], 1);
            }
        }
        __syncthreads();

        if (threadIdx.x < NLIST) {
            int h = hist[threadIdx.x];
            int incl = h;
            for (int o = 1; o < NLIST; o <<= 1) {
                int x = __shfl_up(incl, o, NLIST);
                if ((int)threadIdx.x >= o) incl += x;
            }
            lstart[threadIdx.x] = incl - h;
            offs[threadIdx.x]   = incl - h;
            if (threadIdx.x == NLIST - 1) sh_tot = incl;
            gbase[threadIdx.x] = atomicAdd(&gcur[threadIdx.x], h);
        }
        __syncthreads();

        #pragma unroll
        for (int i = 0; i < BIN_EPT; ++i) {
            int p = myP[i];
            if (p >= 0) {
                int pos = atomicAdd(&offs[p], 1);
                pairs[pos] = myPack[i];
            }
        }
        __syncthreads();

        int tot = sh_tot;
        for (int i = threadIdx.x; i < tot; i += 256) {
            unsigned long long pk = pairs[i];
            int p = (int)(pk >> 32) >> shift;
            int gpos = gbase[p] + (i - lstart[p]);
            if (gpos < listCap) {
                lists[(size_t)p * listCap + gpos] = pk;
            } else {
                int sp = atomicAdd(spillCur, 1);
                if (sp < spillCap) spill[sp] = pk;
            }
        }
        __syncthreads();
    }
}

// Phase 2: re-bin each list into per-window sublists (sequential read,
// LDS sort into <=NB2 bins, coalesced flush runs).
__global__ __launch_bounds__(256) void bin2_kernel(
        const unsigned long long* __restrict__ lists, int listCap,
        const int* __restrict__ gcur,
        unsigned long long* __restrict__ sub, int* __restrict__ cur2,
        unsigned long long* __restrict__ spill, int spillCap,
        int* __restrict__ spillCur, int wpl) {
    __shared__ unsigned long long pr[BIN_CHUNK];
    __shared__ int hist[NB2], lstart[NB2], offs[NB2], gbase[NB2];
    __shared__ int sh_tot;
    int l = blockIdx.x & (NLIST - 1);
    int s = blockIdx.x >> 6;                 // 16 chunk-parallel subs
    int cnt = gcur[l]; if (cnt > listCap) cnt = listCap;
    const unsigned long long* lst = lists + (size_t)l * listCap;
    int wmask = wpl - 1;

    for (int start = s * BIN_CHUNK; start < cnt; start += 16 * BIN_CHUNK) {
        int n = cnt - start; if (n > BIN_CHUNK) n = BIN_CHUNK;
        if (threadIdx.x < NB2) hist[threadIdx.x] = 0;
        __syncthreads();

        unsigned long long my[BIN_EPT]; int myw[BIN_EPT];
        #pragma unroll
        for (int k = 0; k < BIN_EPT; ++k) {
            int i = k * 256 + threadIdx.x;
            if (i < n) {
                unsigned long long pk = lst[start + i];
                int w = ((int)(pk >> 32) >> WSHIFT) & wmask;
                my[k] = pk; myw[k] = w;
                atomicAdd(&hist[w], 1);
            } else myw[k] = -1;
        }
        __syncthreads();

        if (threadIdx.x == 0) {
            int run = 0;
            for (int w = 0; w < wpl; ++w) {
                lstart[w] = run; offs[w] = run; run += hist[w];
            }
            sh_tot = run;
        }
        __syncthreads();
        if ((int)threadIdx.x < wpl)
            gbase[threadIdx.x] =
                atomicAdd(&cur2[l * wpl + threadIdx.x], hist[threadIdx.x]);
        __syncthreads();

        #pragma unroll
        for (int k = 0; k < BIN_EPT; ++k) {
            if (myw[k] >= 0) {
                int pos = atomicAdd(&offs[myw[k]], 1);
                pr[pos] = my[k];
            }
        }
        __syncthreads();

        int tot = sh_tot;
        for (int i = threadIdx.x; i < tot; i += 256) {
            unsigned long long pk = pr[i];
            int w = ((int)(pk >> 32) >> WSHIFT) & wmask;
            int gpos = gbase[w] + (i - lstart[w]);
            if (gpos < CAP2) {
                sub[((size_t)(l * wpl + w)) * CAP2 + gpos] = pk;
            } else {
                int sp = atomicAdd(spillCur, 1);
                if (sp < spillCap) spill[sp] = pk;
            }
        }
        __syncthreads();
    }
}

// Fused gather + LDS max-reduce + single coalesced write-out.
// One block per 128-row window; 32 KB LDS key tile -> 4 blocks/CU.
// REPLAY-SAFETY: sub's content at a fixed address varies between calls, so
// pairs are loaded PER-LANE (divergent addr -> guaranteed vector path) into a
// wave-private LDS slab, then broadcast per edge via uniform-addr ds_read_b64
// (LDS written this dispatch — safe; never s_load through the stale K$).
__global__ __launch_bounds__(512, 8) void fused_kernel(
        const float* __restrict__ feat,
        const unsigned long long* __restrict__ sub,
        const int* __restrict__ cur2,
        float4* __restrict__ out4,
        const int* __restrict__ feat_depth, float* __restrict__ scalar_slot) {
    __shared__ unsigned int tile[WROWS * CCH];      // 32 KB
    __shared__ unsigned long long stage[8][64];     // 4 KB wave-private slabs
    int w = blockIdx.x;
    if (w == 0 && threadIdx.x == 0)
        scalar_slot[0] = (float)(feat_depth[0] + 1);

    for (int i = threadIdx.x; i < WROWS * CCH; i += 512) tile[i] = 0u;
    __syncthreads();

    int cnt = cur2[w]; if (cnt > CAP2) cnt = CAP2;
    const unsigned long long* sl = sub + (size_t)w * CAP2;
    int lane = threadIdx.x & 63;
    int wid = threadIdx.x >> 6;                  // 8 waves

    for (int i0 = wid * 64; i0 < cnt; i0 += 8 * 64) {
        int m = cnt - i0; if (m > 64) m = 64;
        // coalesced 512B per-lane pair load -> wave-private LDS slab
        if (lane < m) stage[wid][lane] = sl[i0 + lane];
        int j = 0;
        for (; j + 8 <= m; j += 8) {
            unsigned long long pk[8];
            #pragma unroll
            for (int u = 0; u < 8; ++u) pk[u] = stage[wid][j + u]; // bcast read
            float f[8]; int rl[8];
            #pragma unroll
            for (int u = 0; u < 8; ++u) {
                int t = (int)(pk[u] & 0xffffffffu);
                rl[u] = ((int)(pk[u] >> 32)) & (WROWS - 1);
                f[u] = feat[(size_t)t * CCH + lane];      // 256B coalesced
            }
            #pragma unroll
            for (int u = 0; u < 8; ++u) {
                unsigned int b = __float_as_uint(f[u]);
                unsigned int key = b ^ ((unsigned int)((int)b >> 31) | 0x80000000u);
                atomicMax(&tile[rl[u] * CCH + lane], key); // ds_max, 2 ln/bank
            }
        }
        for (; j < m; ++j) {
            unsigned long long pk = stage[wid][j];
            int t = (int)(pk & 0xffffffffu);
            int rl = ((int)(pk >> 32)) & (WROWS - 1);
            unsigned int b = __float_as_uint(feat[(size_t)t * CCH + lane]);
            unsigned int key = b ^ ((unsigned int)((int)b >> 31) | 0x80000000u);
            atomicMax(&tile[rl * CCH + lane], key);
        }
    }
    __syncthreads();

    const uint4* t4 = (const uint4*)tile;
    for (int i = threadIdx.x; i < WROWS * CCH / 4; i += 512) {
        uint4 k = t4[i];
        float4 v;
        v.x = (k.x == 0u) ? 0.0f
              : __uint_as_float((k.x & 0x80000000u) ? (k.x ^ 0x80000000u) : ~k.x);
        v.y = (k.y == 0u) ? 0.0f
              : __uint_as_float((k.y & 0x80000000u) ? (k.y ^ 0x80000000u) : ~k.y);
        v.z = (k.z == 0u) ? 0.0f
              : __uint_as_float((k.z & 0x80000000u) ? (k.z ^ 0x80000000u) : ~k.z);
        v.w = (k.w == 0u) ? 0.0f
              : __uint_as_float((k.w & 0x80000000u) ? (k.w ^ 0x80000000u) : ~k.w);
        nt_store_f4(v, out4 + (size_t)w * (WROWS * (CCH / 4)) + i);
    }
}

// Resolve spilled edges (rare): atomic max on top of fused output (only raises).
__global__ __launch_bounds__(256) void spill_kernel(
        const float4* __restrict__ feat4,
        const unsigned long long* __restrict__ spill,
        const int* __restrict__ spillCur, int spillCap,
        float* __restrict__ out) {
    int n = *spillCur; if (n > spillCap) n = spillCap;
    long long total = (long long)n * 16;
    long long stride = (long long)gridDim.x * blockDim.x;
    for (long long i = blockIdx.x * (long long)blockDim.x + threadIdx.x;
         i < total; i += stride) {
        int e = (int)(i >> 4), q = (int)(i & 15);
        unsigned long long pk = spill[e];
        int r = (int)(pk >> 32);
        int t = (int)(pk & 0xffffffffu);
        float4 f = feat4[(size_t)t * 16 + q];
        float* o = out + (size_t)r * CCH + q * 4;
        atomicMaxF(o+0, f.x); atomicMaxF(o+1, f.y);
        atomicMaxF(o+2, f.z); atomicMaxF(o+3, f.w);
    }
}

// If the spill list overflowed, rescan ALL edges with atomic max — idempotent.
__global__ __launch_bounds__(256) void repair_kernel(
        const float4* __restrict__ feat4, const int* __restrict__ src,
        const int* __restrict__ tgt, const int* __restrict__ ntypes,
        const int* __restrict__ spillCur, int spillCap,
        float* __restrict__ out, int E) {
    if (*spillCur <= spillCap) return;
    long long total = (long long)E * 16;
    long long stride = (long long)gridDim.x * blockDim.x;
    for (long long i = blockIdx.x * (long long)blockDim.x + threadIdx.x;
         i < total; i += stride) {
        int e = (int)(i >> 4), q = (int)(i & 15);
        if ((ntypes[e*3] | ntypes[e*3+1] | ntypes[e*3+2]) < 0) continue;
        float4 f = feat4[(size_t)tgt[e] * 16 + q];
        float* o = out + (size_t)src[e] * CCH + q * 4;
        atomicMaxF(o+0, f.x); atomicMaxF(o+1, f.y);
        atomicMaxF(o+2, f.z); atomicMaxF(o+3, f.w);
    }
}

extern "C" void kernel_launch(void* const* d_in, const int* in_sizes, int n_in,
                              void* d_out, int out_size, void* d_ws, size_t ws_size,
                              hipStream_t stream) {
    const float* feat       = (const float*)d_in[0];
    const int*   src_ids    = (const int*)d_in[1];
    const int*   tgt_ids    = (const int*)d_in[2];
    const int*   ntypes     = (const int*)d_in[3];
    const int*   feat_depth = (const int*)d_in[5];
    float* out = (float*)d_out;

    const int E = in_sizes[1];
    const int nout_elems = out_size - 1;
    const int N = nout_elems / CCH;      // output rows
    const int n4 = nout_elems / 4;

    // bin1 shift: rows-per-list = 2^shift1, <= 64 lists
    int shift1 = 0;
    while (((long long)(N - 1) >> shift1) > (NLIST - 1)) ++shift1;
    int wpl = (shift1 >= WSHIFT) ? (1 << (shift1 - WSHIFT)) : 0; // windows/list
    int windows = (wpl > 0) ? ((N + WROWS - 1) >> WSHIFT) : 0;

    // ws ints: gcur[64] | cur2[windows] | spillCur[16] | spill u64[SPILL_CAP]
    //          | lists1 u64[64*LC1] | sub u64[windows*CAP2]
    size_t wsInts = ws_size / sizeof(int);
    size_t zeroInts = (size_t)NLIST + windows + 16;
    int LC1 = 0;
    if (wpl >= 1 && wpl <= NB2 && windows > 0 && (N % WROWS) == 0 &&
        (zeroInts % 4) == 0) {
        for (int lc = 69632; lc >= 49152; lc -= 10240) {
            size_t need = zeroInts + 2ull * SPILL_CAP +
                          2ull * NLIST * lc + 2ull * windows * CAP2;
            if (need <= wsInts) { LC1 = lc; break; }
        }
    }

    if (LC1 == 0) {
        // last-resort: atomic scatter-max
        fill_neginf_kernel<<<2048, 256, 0, stream>>>((float4*)out, n4);
        long long total = (long long)E * 16;
        int blocks = (int)((total + 255) / 256);
        scatter_max_kernel<<<blocks, 256, 0, stream>>>(
            (const float4*)feat, src_ids, tgt_ids, ntypes, out, E);
        finalize_kernel<<<2048, 256, 0, stream>>>(
            (float4*)out, n4, feat_depth, out + nout_elems);
        return;
    }

    int* gcur     = (int*)d_ws;
    int* cur2     = gcur + NLIST;
    int* spillCur = cur2 + windows;
    unsigned long long* spill  = (unsigned long long*)(spillCur + 16);
    unsigned long long* lists1 = spill + SPILL_CAP;
    unsigned long long* sub    = lists1 + (size_t)NLIST * LC1;

    zero4_kernel<<<16, 256, 0, stream>>>((int4*)d_ws, (long long)(zeroInts / 4));

    int numChunks = (E + BIN_CHUNK - 1) / BIN_CHUNK;
    int binGrid = numChunks < 4096 ? numChunks : 4096;
    bin_kernel<<<binGrid, 256, 0, stream>>>(
        src_ids, tgt_ids, ntypes, lists1, LC1, gcur,
        spill, SPILL_CAP, spillCur, shift1, E, numChunks);

    bin2_kernel<<<NLIST * 16, 256, 0, stream>>>(
        lists1, LC1, gcur, sub, cur2, spill, SPILL_CAP, spillCur, wpl);

    fused_kernel<<<windows, 512, 0, stream>>>(
        feat, sub, cur2, (float4*)out, feat_depth, out + nout_elems);

    spill_kernel<<<2048, 256, 0, stream>>>(
        (const float4*)feat, spill, spillCur, SPILL_CAP, out);
    repair_kernel<<<4096, 256, 0, stream>>>(
        (const float4*)feat, src_ids, tgt_ids, ntypes,
        spillCur, SPILL_CAP, out, E);
}